// Round 1
// 956.049 us; speedup vs baseline: 1.0352x; 1.0352x over previous
//
#include <hip/hip_runtime.h>
#include <math.h>

// SoftSkeletonize via the erosion-chain identity:
//   e_0 = img, e_{i+1} = erode(e_i)      (erode = 5-pt cross min, +inf pad)
//   delta_i = relu(e_i - dilate3x3(e_{i+1}))            (dilate pad = -inf)
//   skel: s = delta_0; s += relu(delta_i - s*delta_i), i = 1..40
//
// 5 fused phases (S = 9,8,8,8,8 chain steps). Per 64x64 tile, stage e with
// halo (11 rows / 12 cols) in LDS; S+1 merged passes per phase.
//
// Round-5 changes vs round-4 (989.5 us, LDS-pipe-bound, 3.9e7 bank-conflict
// cycles/dispatch):
//  * STRD 88 -> 92 floats (23 quads/row). With o_quad = (1+2p)*23 + c and
//    idx = 22p + c, o_quad - idx = 23 + 24p === 7 (mod 8): EVERY 8-lane
//    window hits 8 distinct quad-banks for the base read and all constant
//    offsets (+-1 quad, +-23, +46 quads). Staging (23 quads/row) gives
//    o_quad === i (mod 8) -> also conflict-free. Kills the 2-way conflicts
//    the 22-quad stride had at every row-straddling 8-lane group.
//  * Own-patch values live in registers across passes: a0r/a1r = e_{t-1} at
//    the thread's own 2 rows (was re-read as A0/A1 from LDS every pass),
//    ep0/ep1 = e_{t-2} (was re-read as ec0/ec1). Erode loads 8->6, dilate
//    extras 6->4, writeback LDS reads 2->0: ~24% fewer LDS lane-ops.
// LDS: 2 x 86 x 92 x 4B = 63.3 KB (< 64 KB static limit, 2 blocks/CU).
// Border tiles use the same path with +/-INF masks.

#define HH 1024
#define WW 1024
#define T 64
#define MTR 11                 // top row margin  (central rows start at buf row 11)
#define MTC 12                 // left col margin (central cols start at quad 3)
#define RH 86                  // buffer rows
#define STq 22                 // worker quad-cols per row
#define STGQ 23                // staged quads per row (fills the 92-float row)
#define STRD 92                // floats per buffer row (23 quads; 23 % 4 == 3 -> conflict-free)
#define NT 512
#define NIDX 924               // 42 row-pairs x 22 quad-cols

#define LD4(p)    (*(const float4*)(p))
#define ST4(p, v) (*(float4*)(p) = (v))

__device__ __forceinline__ float relu_(float x) { return x > 0.f ? x : 0.f; }
__device__ __forceinline__ float4 min4_(float4 a, float4 b) {
    return make_float4(fminf(a.x,b.x), fminf(a.y,b.y), fminf(a.z,b.z), fminf(a.w,b.w));
}
__device__ __forceinline__ float4 max4_(float4 a, float4 b) {
    return make_float4(fmaxf(a.x,b.x), fmaxf(a.y,b.y), fmaxf(a.z,b.z), fmaxf(a.w,b.w));
}
// 3-tap horizontal min/max of quad a with scalar edges L (col-1), R (col+4)
__device__ __forceinline__ float4 hmin4(float L, float4 a, float R) {
    float4 h;
    h.x = fminf(L,   fminf(a.x, a.y)); h.y = fminf(a.x, fminf(a.y, a.z));
    h.z = fminf(a.y, fminf(a.z, a.w)); h.w = fminf(a.z, fminf(a.w, R));
    return h;
}
__device__ __forceinline__ float4 hmax4(float L, float4 a, float R) {
    float4 h;
    h.x = fmaxf(L,   fmaxf(a.x, a.y)); h.y = fmaxf(a.x, fmaxf(a.y, a.z));
    h.z = fmaxf(a.y, fmaxf(a.z, a.w)); h.w = fmaxf(a.z, fmaxf(a.w, R));
    return h;
}
__device__ __forceinline__ float4 dmask4(float4 v, float rm, float4 cm) {
    // keep if in-image (rm/cm = +INF), else -INF (rm/cm = -INF)
    float4 o;
    o.x = fminf(fminf(v.x, cm.x), rm); o.y = fminf(fminf(v.y, cm.y), rm);
    o.z = fminf(fminf(v.z, cm.z), rm); o.w = fminf(fminf(v.w, cm.w), rm);
    return o;
}
__device__ __forceinline__ void skup(float4& s, float4 e, float4 d, bool init) {
    float4 dl;
    dl.x = relu_(e.x - d.x); dl.y = relu_(e.y - d.y);
    dl.z = relu_(e.z - d.z); dl.w = relu_(e.w - d.w);
    if (init) { s = dl; }
    else {
        s.x += relu_(dl.x - s.x * dl.x); s.y += relu_(dl.y - s.y * dl.y);
        s.z += relu_(dl.z - s.z * dl.z); s.w += relu_(dl.w - s.w * dl.w);
    }
}

__global__ __launch_bounds__(NT, 4) void phase_kernel(
    const float* __restrict__ src, float* __restrict__ dst,
    float* __restrict__ skel, int S, int first, int last)
{
    __shared__ __align__(16) float buf0[RH * STRD + 4];
    __shared__ __align__(16) float buf1[RH * STRD + 4];

    const int h0 = blockIdx.y * T;
    const int w0 = blockIdx.x * T;
    const size_t plane = (size_t)HH * WW;
    const float* sp = src + blockIdx.z * plane;
    float* skp = skel + blockIdx.z * plane;
    float* dp = dst ? dst + blockIdx.z * plane : nullptr;

    const int tid = threadIdx.x;
    const bool border = (h0 == 0) || (w0 == 0) || (h0 + T == HH) || (w0 + T == WW);

    // ---- stage e_{i0} (+inf outside image) into buf0
    if (!border) {
        const float* base = sp + (size_t)(h0 - MTR) * WW + (w0 - MTC);
        for (int i = tid; i < RH * STGQ; i += NT) {
            int r = i / STGQ, q = i - r * STGQ;
            ST4(&buf0[r * STRD + 4 * q], LD4(base + (size_t)r * WW + 4 * q));
        }
    } else {
        for (int i = tid; i < RH * STRD; i += NT) {
            int r = i / STRD, c = i - r * STRD;
            int gh = h0 - MTR + r, gw = w0 - MTC + c;
            float v = INFINITY;
            if ((unsigned)gh < HH && (unsigned)gw < WW) v = sp[(size_t)gh * WW + gw];
            buf0[r * STRD + c] = v;
        }
    }

    // ---- per-round geometry (round q handles idx = tid + NT*q)
    int pq[2], cq[2], oq[2];
    bool act[2], cen[2];
    float4 s0[2], s1[2];
    float4 a0r[2], a1r[2];   // e_{t-1} at own 2 rows (register-resident)
    float4 ep0[2], ep1[2];   // e_{t-2} at own 2 rows (register-resident)
#pragma unroll
    for (int q = 0; q < 2; ++q) {
        int idx = tid + NT * q;
        act[q] = (idx < NIDX);
        int p = idx / STq, c = idx - STq * p;
        pq[q] = p; cq[q] = c;
        oq[q] = (1 + 2 * p) * STRD + 4 * c;
        cen[q] = act[q] && (p >= 5) && (p <= 36) && (c >= 3) && (c <= 18);
    }
    if (!first) {
#pragma unroll
        for (int q = 0; q < 2; ++q) if (cen[q]) {
            const float* g = skp + (size_t)(h0 + 2 * pq[q] - 10) * WW + (w0 + 4 * cq[q] - 12);
            s0[q] = LD4(g); s1[q] = LD4(g + WW);
        }
    }
    __syncthreads();

    // ---- init register-resident own rows from staged e_{i0}
#pragma unroll
    for (int q = 0; q < 2; ++q) if (act[q]) {
        a0r[q] = LD4(buf0 + oq[q]);
        a1r[q] = LD4(buf0 + oq[q] + STRD);
    }

    for (int t = 1; t <= S + 1; ++t) {
        float* sb = ((t - 1) & 1) ? buf1 : buf0;
        float* db = (t & 1) ? buf1 : buf0;
        const bool do_er = (t <= S);
        const bool do_dl = (t >= 2);
        const bool init = (first != 0) && (t == 2);
#pragma unroll
        for (int q = 0; q < 2; ++q) {
            if (!act[q]) continue;
            const bool cw = cen[q] && do_dl;
            if (!(do_er || cw)) continue;
            const int o = oq[q];
            // shared loads: vertical neighbors + horizontal edge quads.
            // Own rows (A0/A1) and own e_{t-2} come from registers.
            float4 U   = LD4(sb + o - STRD);
            float4 Am0 = LD4(sb + o - 4);
            float4 Ap0 = LD4(sb + o + 4);
            float4 Am1 = LD4(sb + o + STRD - 4);
            float4 Ap1 = LD4(sb + o + STRD + 4);
            float4 D   = LD4(sb + o + 2 * STRD);
            float4 A0 = a0r[q], A1 = a1r[q];
            float4 Um, Up, Dm, Dp;
            if (cw) {   // extra edges for dilate rows r-1, r+2
                Um = LD4(sb + o - STRD - 4);
                Up = LD4(sb + o - STRD + 4);
                Dm = LD4(sb + o + 2 * STRD - 4);
                Dp = LD4(sb + o + 2 * STRD + 4);
            }
            float4 e0, e1;
            if (do_er) {
                float4 h0q = hmin4(Am0.w, A0, Ap0.x);
                float4 h1q = hmin4(Am1.w, A1, Ap1.x);
                e0 = min4_(min4_(U, A1), h0q);   // min(row r-1, row r+1, hmin row r)
                e1 = min4_(min4_(A0, D), h1q);
                if (border) {   // force +inf outside image
                    int ghb = h0 - MTR + 1 + 2 * pq[q];
                    int gwb = w0 - MTC + 4 * cq[q];
                    float4 cwm;
                    cwm.x = (unsigned)(gwb + 0) < WW ? -INFINITY : INFINITY;
                    cwm.y = (unsigned)(gwb + 1) < WW ? -INFINITY : INFINITY;
                    cwm.z = (unsigned)(gwb + 2) < WW ? -INFINITY : INFINITY;
                    cwm.w = (unsigned)(gwb + 3) < WW ? -INFINITY : INFINITY;
                    float r0 = (unsigned)ghb       < HH ? -INFINITY : INFINITY;
                    float r1 = (unsigned)(ghb + 1) < HH ? -INFINITY : INFINITY;
                    e0 = max4_(e0, max4_(make_float4(r0, r0, r0, r0), cwm));
                    e1 = max4_(e1, max4_(make_float4(r1, r1, r1, r1), cwm));
                }
                ST4(db + o, e0);
                ST4(db + o + STRD, e1);
            }
            if (cw) {
                float4 tU = U, tA = A0, tB = A1, tD = D;
                float eUm = Um.w, eUp = Up.x, eAm = Am0.w, eAp = Ap0.x;
                float eBm = Am1.w, eBp = Ap1.x, eDm = Dm.w, eDp = Dp.x;
                if (border) {   // force -inf outside image before hmax
                    int ghb = h0 - MTR + 1 + 2 * pq[q];
                    int gwb = w0 - MTC + 4 * cq[q];
                    float rm0 = (unsigned)(ghb - 1) < HH ? INFINITY : -INFINITY;
                    float rm1 = (unsigned)(ghb)     < HH ? INFINITY : -INFINITY;
                    float rm2 = (unsigned)(ghb + 1) < HH ? INFINITY : -INFINITY;
                    float rm3 = (unsigned)(ghb + 2) < HH ? INFINITY : -INFINITY;
                    float cmL = (unsigned)(gwb - 1) < WW ? INFINITY : -INFINITY;
                    float cmR = (unsigned)(gwb + 4) < WW ? INFINITY : -INFINITY;
                    float4 cmC;
                    cmC.x = (unsigned)(gwb + 0) < WW ? INFINITY : -INFINITY;
                    cmC.y = (unsigned)(gwb + 1) < WW ? INFINITY : -INFINITY;
                    cmC.z = (unsigned)(gwb + 2) < WW ? INFINITY : -INFINITY;
                    cmC.w = (unsigned)(gwb + 3) < WW ? INFINITY : -INFINITY;
                    tU = dmask4(tU, rm0, cmC); tA = dmask4(tA, rm1, cmC);
                    tB = dmask4(tB, rm2, cmC); tD = dmask4(tD, rm3, cmC);
                    eUm = fminf(fminf(eUm, cmL), rm0); eUp = fminf(fminf(eUp, cmR), rm0);
                    eAm = fminf(fminf(eAm, cmL), rm1); eAp = fminf(fminf(eAp, cmR), rm1);
                    eBm = fminf(fminf(eBm, cmL), rm2); eBp = fminf(fminf(eBp, cmR), rm2);
                    eDm = fminf(fminf(eDm, cmL), rm3); eDp = fminf(fminf(eDp, cmR), rm3);
                }
                float4 hU = hmax4(eUm, tU, eUp);
                float4 hA = hmax4(eAm, tA, eAp);
                float4 hB = hmax4(eBm, tB, eBp);
                float4 hD = hmax4(eDm, tD, eDp);
                float4 d0 = max4_(hU, max4_(hA, hB));
                float4 d1 = max4_(hA, max4_(hB, hD));
                skup(s0[q], ep0[q], d0, init);   // e_{t-2} from registers
                skup(s1[q], ep1[q], d1, init);
            }
            if (do_er) {   // rotate AFTER dilate/skup consumed e_{t-2}
                ep0[q] = A0; ep1[q] = A1;
                a0r[q] = e0; a1r[q] = e1;
            }
        }
        __syncthreads();
    }

    // ---- writeback: skel always; e_S central (from registers) if not last phase
#pragma unroll
    for (int q = 0; q < 2; ++q) if (cen[q]) {
        size_t grow = (size_t)(h0 + 2 * pq[q] - 10) * WW + (w0 + 4 * cq[q] - 12);
        ST4(skp + grow, s0[q]);
        ST4(skp + grow + WW, s1[q]);
        if (!last) {
            ST4(dp + grow, a0r[q]);
            ST4(dp + grow + WW, a1r[q]);
        }
    }
}

extern "C" void kernel_launch(void* const* d_in, const int* in_sizes, int n_in,
                              void* d_out, int out_size, void* d_ws, size_t ws_size,
                              hipStream_t stream) {
    const float* img = (const float*)d_in[0];
    float* skel = (float*)d_out;
    const int B = in_sizes[0] / (HH * WW);  // 16
    const size_t plane = (size_t)HH * WW;

    float* e0 = (float*)d_ws;
    float* e1 = e0 + (size_t)B * plane;

    dim3 grid(WW / T, HH / T, B);
    dim3 block(NT);

    const int Ks[5] = {9, 8, 8, 8, 8};   // 41 deltas total (init + 40 iters)
    const float* src = img;
    float* ebufs[2] = {e0, e1};
    for (int p = 0; p < 5; ++p) {
        int first = (p == 0), last = (p == 4);
        float* dstp = last ? nullptr : ebufs[p & 1];
        phase_kernel<<<grid, block, 0, stream>>>(src, dstp, skel, Ks[p], first, last);
        src = dstp;
    }
}